// Round 6
// baseline (382.946 us; speedup 1.0000x reference)
//
#include <hip/hip_runtime.h>
#include <math.h>

#define NBLK    640
#define NTHR    256
#define NWAVES  (NBLK * 4)      // 2560
#define SUBT    (NBLK / 16)     // 40

#define HID_N   10000
#define MID_N   5000
#define NPOS_N  1001
#define NOUT_N  2001
#define W2COLS  6001
#define LQ3     (2048 * 3)

__device__ __forceinline__ float frcp(float x) { return __builtin_amdgcn_rcpf(x); }
__device__ __forceinline__ float fsig(float x) { return frcp(1.0f + __expf(-x)); }
__device__ __forceinline__ float ftanh(float x) {
    float t = __expf(2.0f * x);
    return (t - 1.0f) * frcp(t + 1.0f);
}
__device__ __forceinline__ float dot4(float4 a, float4 b) {
    return a.x * b.x + a.y * b.y + a.z * b.z + a.w * b.w;
}
__device__ __forceinline__ float wave_reduce(float acc) {
    #pragma unroll
    for (int off = 32; off > 0; off >>= 1) acc += __shfl_down(acc, off, 64);
    return acc;
}

// ONE grid barrier: release-add, RELAXED poll (no per-poll L2 invalidate),
// single ACQUIRE load after the spin exits. 16 sub-counters + master at bar[16].
__device__ __forceinline__ void grid_barrier(unsigned* bar) {
    __syncthreads();
    if (threadIdx.x == 0) {
        unsigned old = __hip_atomic_fetch_add(&bar[blockIdx.x & 15], 1u,
                                              __ATOMIC_RELEASE, __HIP_MEMORY_SCOPE_AGENT);
        if (old == SUBT - 1)
            __hip_atomic_fetch_add(&bar[16], 1u, __ATOMIC_RELEASE, __HIP_MEMORY_SCOPE_AGENT);
        while (__hip_atomic_load(&bar[16], __ATOMIC_RELAXED, __HIP_MEMORY_SCOPE_AGENT) < 16u)
            __builtin_amdgcn_s_sleep(8);
        // single acquire: discard stale cached lines once, after everyone arrived
        (void)__hip_atomic_load(&bar[16], __ATOMIC_ACQUIRE, __HIP_MEMORY_SCOPE_AGENT);
    }
    __syncthreads();
}

__global__ void __launch_bounds__(256, 3) fused_all(
    const float* __restrict__ quotes, const float* __restrict__ pos,
    const float* __restrict__ wih0, const float* __restrict__ bih0, const float* __restrict__ bhh0,
    const float* __restrict__ wih1, const float* __restrict__ bih1, const float* __restrict__ bhh1,
    const float* __restrict__ wih2, const float* __restrict__ bih2, const float* __restrict__ bhh2,
    const float* __restrict__ w1, const float* __restrict__ b1,
    const float* __restrict__ w2, const float* __restrict__ b2,
    unsigned* __restrict__ bar, float* __restrict__ vcat_g,
    float* __restrict__ out)
{
    __shared__ __align__(16) float s_conc[HID_N + 16];  // conc, later reused as vcat (6016)
    __shared__ float s_w[1160];                          // staged small weights

    const int tid  = threadIdx.x;
    const int lane = tid & 63;
    const int wid  = tid >> 6;
    const int gw   = blockIdx.x * 4 + wid;

    // ---- stage small head weights -> LDS ----
    for (int j = tid; j < 120; j += NTHR) s_w[j]        = wih0[j];
    for (int j = tid; j < 40;  j += NTHR) s_w[120 + j]  = bih0[j];
    for (int j = tid; j < 40;  j += NTHR) s_w[160 + j]  = bhh0[j];
    for (int j = tid; j < 400; j += NTHR) s_w[200 + j]  = wih1[j];
    for (int j = tid; j < 40;  j += NTHR) s_w[600 + j]  = bih1[j];
    for (int j = tid; j < 40;  j += NTHR) s_w[640 + j]  = bhh1[j];
    for (int j = tid; j < 400; j += NTHR) s_w[680 + j]  = wih2[j];
    for (int j = tid; j < 40;  j += NTHR) s_w[1080 + j] = bih2[j];
    for (int j = tid; j < 40;  j += NTHR) s_w[1120 + j] = bhh2[j];

    // quotes last-timestep for my head rows -> regs
    float q0[4], q1[4], q2[4];
    #pragma unroll
    for (int u = 0; u < 4; ++u) {
        int a = tid + u * NTHR;
        if (a < 1000) {
            const float* qp = quotes + (size_t)a * LQ3 + (LQ3 - 3);
            q0[u] = qp[0]; q1[u] = qp[1]; q2[u] = qp[2];
        } else { q0[u] = q1[u] = q2[u] = 0.0f; }
    }

    __syncthreads();  // s_w ready

    // ---- issue w2 prefetch into registers (overlaps head compute below) ----
    float w2g[94];
    if (gw < NOUT_N) {
        const float* wr = w2 + (size_t)gw * W2COLS;
        #pragma unroll
        for (int j = 0; j < 93; ++j) w2g[j] = wr[lane + 64 * j];
        int c93 = 5952 + lane;
        w2g[93] = (c93 < W2COLS) ? wr[c93] : 0.0f;
    }

    // ---- head compute (VALU + LDS only; f-gate dead, skipped) ----
    #pragma unroll 1
    for (int u = 0; u < 4; ++u) {
        int a = tid + u * NTHR;
        if (a < 1000) {
            float h1[10], h2[10];
            #pragma unroll
            for (int k = 0; k < 10; ++k) {
                float gi = q0[u]*s_w[3*k]      + q1[u]*s_w[3*k+1]      + q2[u]*s_w[3*k+2]      + s_w[120+k]    + s_w[160+k];
                float gg = q0[u]*s_w[3*(20+k)] + q1[u]*s_w[3*(20+k)+1] + q2[u]*s_w[3*(20+k)+2] + s_w[140+k]    + s_w[180+k];
                float go = q0[u]*s_w[3*(30+k)] + q1[u]*s_w[3*(30+k)+1] + q2[u]*s_w[3*(30+k)+2] + s_w[150+k]    + s_w[190+k];
                h1[k] = fsig(go) * ftanh(fsig(gi) * ftanh(gg));
            }
            #pragma unroll
            for (int k = 0; k < 10; ++k) {
                float gi = s_w[600+k]    + s_w[640+k];
                float gg = s_w[620+k]    + s_w[660+k];
                float go = s_w[630+k]    + s_w[670+k];
                #pragma unroll
                for (int m = 0; m < 10; ++m) {
                    gi += h1[m] * s_w[200 + k*10 + m];
                    gg += h1[m] * s_w[200 + (20+k)*10 + m];
                    go += h1[m] * s_w[200 + (30+k)*10 + m];
                }
                h2[k] = fsig(go) * ftanh(fsig(gi) * ftanh(gg));
            }
            #pragma unroll
            for (int k = 0; k < 10; ++k) {
                float gi = s_w[1080+k]   + s_w[1120+k];
                float gg = s_w[1100+k]   + s_w[1140+k];
                float go = s_w[1110+k]   + s_w[1150+k];
                #pragma unroll
                for (int m = 0; m < 10; ++m) {
                    gi += h2[m] * s_w[680 + k*10 + m];
                    gg += h2[m] * s_w[680 + (20+k)*10 + m];
                    go += h2[m] * s_w[680 + (30+k)*10 + m];
                }
                float hh = fsig(go) * ftanh(fsig(gi) * ftanh(gg));
                s_conc[a * 10 + k] = ftanh(hh);
            }
        }
    }

    __syncthreads();  // s_conc ready

    // ---- pos -> vcat tail (block 0), before barrier ----
    if (blockIdx.x == 0) {
        for (int j = tid; j < NPOS_N; j += NTHR) vcat_g[MID_N + j] = pos[j];
        if (tid < 3) vcat_g[W2COLS + tid] = 0.0f;
    }

    // ---- phase A: w1 rows (one per wave, <=2 per wave), conc from LDS ----
    {
        const float4* cvl = reinterpret_cast<const float4*>(s_conc);
        #pragma unroll 1
        for (int r = gw; r < MID_N; r += NWAVES) {
            const float4* rb = reinterpret_cast<const float4*>(w1 + (size_t)r * HID_N);
            float a0 = 0.f, a1 = 0.f, a2 = 0.f, a3 = 0.f;
            int i = lane;
            #pragma unroll 1
            for (int kk = 0; kk < 9; ++kk, i += 256) {
                float4 x0 = rb[i];       float4 x1 = rb[i + 64];
                float4 x2 = rb[i + 128]; float4 x3 = rb[i + 192];
                float4 c0 = cvl[i];       float4 c1 = cvl[i + 64];
                float4 c2 = cvl[i + 128]; float4 c3 = cvl[i + 192];
                a0 += dot4(x0, c0); a1 += dot4(x1, c1);
                a2 += dot4(x2, c2); a3 += dot4(x3, c3);
            }
            {   // i = lane + 2304; remaining 196 = 3*64 + 4
                float4 x0 = rb[i];       float4 x1 = rb[i + 64];  float4 x2 = rb[i + 128];
                float4 c0 = cvl[i];      float4 c1 = cvl[i + 64]; float4 c2 = cvl[i + 128];
                a0 += dot4(x0, c0); a1 += dot4(x1, c1); a2 += dot4(x2, c2);
            }
            if (lane < 4) {
                float4 x = rb[2496 + lane], c = cvl[2496 + lane];
                a3 += dot4(x, c);
            }
            float acc = wave_reduce((a0 + a1) + (a2 + a3));
            if (lane == 0) vcat_g[r] = ftanh(acc + b1[r]);
        }
    }

    grid_barrier(bar);

    // blocks with no phase-C rows are done
    if (blockIdx.x * 4 >= NOUT_N) return;

    // ---- vcat -> LDS (reuse s_conc), zero pad [6004,6016) ----
    for (int j = tid; j < 6016; j += NTHR)
        s_conc[j] = (j < 6004) ? vcat_g[j] : 0.0f;
    __syncthreads();

    // ---- phase C: register-held w2 row . vcat(LDS) ----
    if (gw < NOUT_N) {
        float acc = 0.0f;
        #pragma unroll
        for (int j = 0; j < 94; ++j)
            acc += w2g[j] * s_conc[lane + 64 * j];
        acc = wave_reduce(acc);
        if (lane == 0) out[gw] = acc + b2[gw];
    }
}

extern "C" void kernel_launch(void* const* d_in, const int* in_sizes, int n_in,
                              void* d_out, int out_size, void* d_ws, size_t ws_size,
                              hipStream_t stream)
{
    const float* quotes = (const float*)d_in[0];
    const float* pos    = (const float*)d_in[1];
    const float* wih0   = (const float*)d_in[2];
    const float* bih0   = (const float*)d_in[4];
    const float* bhh0   = (const float*)d_in[5];
    const float* wih1   = (const float*)d_in[6];
    const float* bih1   = (const float*)d_in[8];
    const float* bhh1   = (const float*)d_in[9];
    const float* wih2   = (const float*)d_in[10];
    const float* bih2   = (const float*)d_in[12];
    const float* bhh2   = (const float*)d_in[13];
    const float* w1     = (const float*)d_in[14];
    const float* b1     = (const float*)d_in[15];
    const float* w2     = (const float*)d_in[16];
    const float* b2     = (const float*)d_in[17];
    float* out = (float*)d_out;

    unsigned* bar  = (unsigned*)d_ws;                       // 64 u32, zeroed per call
    float*    vcat = (float*)((char*)d_ws + 256);           // 6016 floats

    (void)hipMemsetAsync(d_ws, 0, 256, stream);

    fused_all<<<NBLK, NTHR, 0, stream>>>(
        quotes, pos,
        wih0, bih0, bhh0, wih1, bih1, bhh1, wih2, bih2, bhh2,
        w1, b1, w2, b2,
        bar, vcat, out);
}

// Round 8
// 65.205 us; speedup vs baseline: 5.8730x; 5.8730x over previous
//
#include <hip/hip_runtime.h>
#include <math.h>

#define A_N    1000
#define LQ_N   2048
#define C_N    3
#define H_N    10
#define HID_N  10000   // A_N * H_N
#define MID_N  5000
#define NPOS_N 1001
#define NOUT_N 2001
#define W2COLS 6001    // MID_N + NPOS_N

typedef float f4 __attribute__((ext_vector_type(4)));

__device__ __forceinline__ float sigmoidf_(float x) { return 1.0f / (1.0f + expf(-x)); }

__device__ __forceinline__ float dot4v(f4 a, f4 b) {
    return a.x * b.x + a.y * b.y + a.z * b.z + a.w * b.w;
}
__device__ __forceinline__ float wave_reduce(float acc) {
    #pragma unroll
    for (int off = 32; off > 0; off >>= 1) acc += __shfl_down(acc, off, 64);
    return acc;
}

// Kernel A: blocks 0-3: lstm head -> conc ; block 4: pos -> vcat[5000:], pad zeros
__global__ void __launch_bounds__(256) lstm_head(
    const float* __restrict__ quotes,
    const float* __restrict__ wih0, const float* __restrict__ bih0, const float* __restrict__ bhh0,
    const float* __restrict__ wih1, const float* __restrict__ bih1, const float* __restrict__ bhh1,
    const float* __restrict__ wih2, const float* __restrict__ bih2, const float* __restrict__ bhh2,
    const float* __restrict__ pos,
    float* __restrict__ conc, float* __restrict__ vcat)
{
    if (blockIdx.x == 4) {
        for (int j = threadIdx.x; j < NPOS_N; j += 256)
            vcat[MID_N + j] = pos[j];
        if (threadIdx.x < 3) vcat[W2COLS + threadIdx.x] = 0.0f;
        return;
    }

    int a = blockIdx.x * blockDim.x + threadIdx.x;
    if (a >= A_N) return;

    const float* q = quotes + (size_t)a * LQ_N * C_N + (size_t)(LQ_N - 1) * C_N;
    float x0 = q[0], x1 = q[1], x2 = q[2];

    float g[40];
    float h[H_N];

    #pragma unroll
    for (int j = 0; j < 40; ++j)
        g[j] = x0 * wih0[j * 3 + 0] + x1 * wih0[j * 3 + 1] + x2 * wih0[j * 3 + 2]
             + bih0[j] + bhh0[j];
    #pragma unroll
    for (int k = 0; k < H_N; ++k) {
        float cc = sigmoidf_(g[k]) * tanhf(g[20 + k]);
        h[k] = sigmoidf_(g[30 + k]) * tanhf(cc);
    }

    #pragma unroll
    for (int j = 0; j < 40; ++j) {
        float s = bih1[j] + bhh1[j];
        #pragma unroll
        for (int k = 0; k < H_N; ++k) s += h[k] * wih1[j * 10 + k];
        g[j] = s;
    }
    float h2[H_N];
    #pragma unroll
    for (int k = 0; k < H_N; ++k) {
        float cc = sigmoidf_(g[k]) * tanhf(g[20 + k]);
        h2[k] = sigmoidf_(g[30 + k]) * tanhf(cc);
    }

    #pragma unroll
    for (int j = 0; j < 40; ++j) {
        float s = bih2[j] + bhh2[j];
        #pragma unroll
        for (int k = 0; k < H_N; ++k) s += h2[k] * wih2[j * 10 + k];
        g[j] = s;
    }
    #pragma unroll
    for (int k = 0; k < H_N; ++k) {
        float cc = sigmoidf_(g[k]) * tanhf(g[20 + k]);
        float hh = sigmoidf_(g[30 + k]) * tanhf(cc);
        conc[a * H_N + k] = tanhf(hh);
    }
}

// Kernel B: lin(vcat[0:5000]) = tanh(conc @ w1.T + b1). 1 wave/row, 4-deep float4 ILP.
// w1 loads NON-TEMPORAL (single-use stream; avoid evicting dirty poison lines from L2/L3).
__global__ void __launch_bounds__(256) mv1(
    const float* __restrict__ w1, const float* __restrict__ b1,
    const float* __restrict__ conc, float* __restrict__ vcat)
{
    int lane = threadIdx.x & 63;
    int wid  = threadIdx.x >> 6;
    int row  = blockIdx.x * 4 + wid;           // < 5000 always (grid = 1250)

    const f4* rb = reinterpret_cast<const f4*>(w1 + (size_t)row * HID_N);
    const f4* cv = reinterpret_cast<const f4*>(conc);

    float acc0 = 0.f, acc1 = 0.f, acc2 = 0.f, acc3 = 0.f;
    int i = lane;
    #pragma unroll 1
    for (int k = 0; k < 9; ++k, i += 256) {
        f4 a0 = __builtin_nontemporal_load(rb + i);
        f4 a1 = __builtin_nontemporal_load(rb + i + 64);
        f4 a2 = __builtin_nontemporal_load(rb + i + 128);
        f4 a3 = __builtin_nontemporal_load(rb + i + 192);
        f4 c0 = cv[i];       f4 c1 = cv[i + 64];
        f4 c2 = cv[i + 128]; f4 c3 = cv[i + 192];
        acc0 += dot4v(a0, c0);
        acc1 += dot4v(a1, c1);
        acc2 += dot4v(a2, c2);
        acc3 += dot4v(a3, c3);
    }
    // i = lane + 2304 ; remaining 196 float4 = 3*64 + 4
    {
        f4 a0 = __builtin_nontemporal_load(rb + i);
        f4 a1 = __builtin_nontemporal_load(rb + i + 64);
        f4 a2 = __builtin_nontemporal_load(rb + i + 128);
        f4 c0 = cv[i];       f4 c1 = cv[i + 64];  f4 c2 = cv[i + 128];
        acc0 += dot4v(a0, c0);
        acc1 += dot4v(a1, c1);
        acc2 += dot4v(a2, c2);
    }
    if (lane < 4) {
        f4 a = __builtin_nontemporal_load(rb + 2496 + lane);
        f4 c = cv[2496 + lane];
        acc3 += dot4v(a, c);
    }

    float acc = wave_reduce((acc0 + acc1) + (acc2 + acc3));
    if (lane == 0) vcat[row] = tanhf(acc + b1[row]);
}

// Kernel C: out[r] = w2[r,:] . vcat + b2[r]. Full 6001-col row, aligned float4 body,
// scalar prologue/tail, 4-deep ILP. w2 loads NON-TEMPORAL; vcat gathers stay cached (L1).
__global__ void __launch_bounds__(256) mv2(
    const float* __restrict__ w2, const float* __restrict__ b2,
    const float* __restrict__ vcat, float* __restrict__ out)
{
    int lane = threadIdx.x & 63;
    int wid  = threadIdx.x >> 6;
    int row  = blockIdx.x * 4 + wid;
    if (row >= NOUT_N) return;

    const float* wr = w2 + (size_t)row * W2COLS;
    const int p    = (4 - (row & 3)) & 3;      // (row*6001) % 4 == row % 4
    const int n    = W2COLS - p;
    const int n4   = n >> 2;                   // ~1500
    const int tail = n & 3;

    float acc0 = 0.f, acc1 = 0.f, acc2 = 0.f, acc3 = 0.f;
    if (lane < p) acc0 += wr[lane] * vcat[lane];

    const f4* rb = reinterpret_cast<const f4*>(wr + p);
    int i = lane;
    #pragma unroll 1
    for (; i + 192 < n4; i += 256) {
        f4 a0 = __builtin_nontemporal_load(rb + i);
        f4 a1 = __builtin_nontemporal_load(rb + i + 64);
        f4 a2 = __builtin_nontemporal_load(rb + i + 128);
        f4 a3 = __builtin_nontemporal_load(rb + i + 192);
        int j0 = p + 4 * i, j1 = j0 + 256, j2 = j0 + 512, j3 = j0 + 768;
        acc0 += a0.x * vcat[j0] + a0.y * vcat[j0+1] + a0.z * vcat[j0+2] + a0.w * vcat[j0+3];
        acc1 += a1.x * vcat[j1] + a1.y * vcat[j1+1] + a1.z * vcat[j1+2] + a1.w * vcat[j1+3];
        acc2 += a2.x * vcat[j2] + a2.y * vcat[j2+1] + a2.z * vcat[j2+2] + a2.w * vcat[j2+3];
        acc3 += a3.x * vcat[j3] + a3.y * vcat[j3+1] + a3.z * vcat[j3+2] + a3.w * vcat[j3+3];
    }
    #pragma unroll 1
    for (; i < n4; i += 64) {
        f4 a = __builtin_nontemporal_load(rb + i);
        int j = p + 4 * i;
        acc0 += a.x * vcat[j] + a.y * vcat[j+1] + a.z * vcat[j+2] + a.w * vcat[j+3];
    }
    if (lane < tail) {
        int j = p + 4 * n4 + lane;
        acc0 += wr[j] * vcat[j];
    }

    float s = wave_reduce((acc0 + acc1) + (acc2 + acc3));
    if (lane == 0) out[row] = s + b2[row];
}

extern "C" void kernel_launch(void* const* d_in, const int* in_sizes, int n_in,
                              void* d_out, int out_size, void* d_ws, size_t ws_size,
                              hipStream_t stream)
{
    const float* quotes = (const float*)d_in[0];
    const float* pos    = (const float*)d_in[1];
    const float* wih0   = (const float*)d_in[2];
    const float* bih0   = (const float*)d_in[4];
    const float* bhh0   = (const float*)d_in[5];
    const float* wih1   = (const float*)d_in[6];
    const float* bih1   = (const float*)d_in[8];
    const float* bhh1   = (const float*)d_in[9];
    const float* wih2   = (const float*)d_in[10];
    const float* bih2   = (const float*)d_in[12];
    const float* bhh2   = (const float*)d_in[13];
    const float* w1     = (const float*)d_in[14];
    const float* b1     = (const float*)d_in[15];
    const float* w2     = (const float*)d_in[16];
    const float* b2     = (const float*)d_in[17];
    float* out = (float*)d_out;

    float* vcat = (float*)d_ws;           // 6004+pad floats: [lin | pos | pad]
    float* conc = vcat + 6016;            // HID_N floats, 16B-aligned offset

    lstm_head<<<5, 256, 0, stream>>>(
        quotes, wih0, bih0, bhh0, wih1, bih1, bhh1, wih2, bih2, bhh2,
        pos, conc, vcat);

    mv1<<<MID_N / 4, 256, 0, stream>>>(w1, b1, conc, vcat);

    mv2<<<(NOUT_N + 3) / 4, 256, 0, stream>>>(w2, b2, vcat, out);
}